// Round 1
// baseline (55.745 us; speedup 1.0000x reference)
//
#include <hip/hip_runtime.h>
#include <math.h>

#define CCH 256
#define HMD 128
#define HW (HMD*HMD)          // 16384
#define NTOT (8*HW)           // 131072 per channel
#define OH 11
#define OW 8
#define NPIX (OH*OW)          // 88
#define NPAIR 16

// ws float layout:
// [0..255]    sum[c]
// [256..511]  sumsq[c]
// [512..767]  s[c]
// [768..1023] t[c]
// [1024..1039] pd2[pair]
// [1040..1055] nd2[pair]
// [1056] focal loss sum, [1057] num_pos
#define WS_SUM   0
#define WS_SUMSQ 256
#define WS_S     512
#define WS_T     768
#define WS_PD2   1024
#define WS_ND2   1040
#define WS_LOSS  1056
#define WS_NPOS  1057
#define WS_NZERO 1058

__device__ __forceinline__ void block_reduce2(float& a, float& b) {
    // assumes blockDim.x == 256
    #pragma unroll
    for (int off = 32; off > 0; off >>= 1) {
        a += __shfl_down(a, off, 64);
        b += __shfl_down(b, off, 64);
    }
    __shared__ float sa[4], sb[4];
    int wid  = threadIdx.x >> 6;
    int lane = threadIdx.x & 63;
    if (lane == 0) { sa[wid] = a; sb[wid] = b; }
    __syncthreads();
    if (threadIdx.x == 0) {
        a = sa[0] + sa[1] + sa[2] + sa[3];
        b = sb[0] + sb[1] + sb[2] + sb[3];
    }
}

// grid = 2048 (b*256+c), block = 256. Each block reduces one 16384-elem plane.
__global__ void chan_sums(const float* __restrict__ simi, float* __restrict__ ws) {
    const float4* p = (const float4*)(simi + (size_t)blockIdx.x * HW);
    int tid = threadIdx.x;
    float s = 0.f, s2 = 0.f;
    #pragma unroll
    for (int it = 0; it < 16; ++it) {
        float4 v = p[it * 256 + tid];
        s  += v.x + v.y + v.z + v.w;
        s2 += v.x*v.x + v.y*v.y + v.z*v.z + v.w*v.w;
    }
    block_reduce2(s, s2);
    if (tid == 0) {
        int c = blockIdx.x & 255;
        atomicAdd(&ws[WS_SUM + c], s);
        atomicAdd(&ws[WS_SUMSQ + c], s2);
    }
}

// 1 block, 256 threads
__global__ void scales(const float* __restrict__ gamma, const float* __restrict__ beta,
                       float* __restrict__ ws) {
    int c = threadIdx.x;
    const float invn = 1.0f / (float)NTOT;
    float mean = ws[WS_SUM + c] * invn;
    float var  = ws[WS_SUMSQ + c] * invn - mean * mean;
    float rstd = 1.0f / sqrtf(var + 1e-5f);
    float sc = gamma[c] * rstd;
    ws[WS_S + c] = sc;
    ws[WS_T + c] = beta[c] - mean * sc;
}

// grid = NPAIR*8 blocks, block = 256. blockIdx.x = pair*8 + slice.
// Each block handles 32 channels x 88 positions for one (anchor,positive,negative) triple.
__global__ void triplet_partial(const float* __restrict__ simi,
                                const int* __restrict__ bboxf,
                                const int* __restrict__ bboxm,
                                const float* __restrict__ ws,
                                float* __restrict__ ws_out) {
    int pair  = blockIdx.x >> 3;
    int slice = blockIdx.x & 7;
    int tid = threadIdx.x;

    __shared__ int   sYA[3][OH], sYB[3][OH], sXA[3][OW], sXB[3][OW];
    __shared__ float sWY[3][OH], sWX[3][OW];
    __shared__ int   sBase[3];

    if (tid < 3) {
        const int* bx;
        int bidx;
        if (tid == 0)      { bx = bboxf + pair * 4;        bidx = pair >> 2; }       // anchor
        else if (tid == 1) { bx = bboxf + (16 + pair) * 4; bidx = 4 + (pair >> 2); } // positive
        else               { bx = bboxm + pair * 4;        bidx = pair >> 1; }       // negative
        int x0 = bx[0], y0 = bx[1], x1 = bx[2], y1 = bx[3];
        float h = (float)(y1 - y0), w = (float)(x1 - x0);
        for (int j = 0; j < OH; ++j) {
            float sy = fminf(fmaxf((j + 0.5f) * h / (float)OH - 0.5f, 0.0f), h - 1.0f);
            int ylo = (int)floorf(sy);
            int yhi = min(ylo + 1, y1 - y0 - 1);
            sYA[tid][j] = y0 + ylo;
            sYB[tid][j] = y0 + yhi;
            sWY[tid][j] = sy - (float)ylo;
        }
        for (int j = 0; j < OW; ++j) {
            float sx = fminf(fmaxf((j + 0.5f) * w / (float)OW - 0.5f, 0.0f), w - 1.0f);
            int xlo = (int)floorf(sx);
            int xhi = min(xlo + 1, x1 - x0 - 1);
            sXA[tid][j] = x0 + xlo;
            sXB[tid][j] = x0 + xhi;
            sWX[tid][j] = sx - (float)xlo;
        }
        sBase[tid] = bidx * CCH * HW;
    }
    __syncthreads();

    float spd = 0.f, snd = 0.f;
    for (int e = tid; e < 32 * NPIX; e += 256) {
        int c = slice * 32 + e / NPIX;
        int p = e % NPIX;
        int y = p >> 3, x = p & 7;
        float sc = ws[WS_S + c], tc = ws[WS_T + c];
        float vals[3];
        #pragma unroll
        for (int k = 0; k < 3; ++k) {
            const float* img = simi + sBase[k] + c * HW;
            float wy = sWY[k][y], wx = sWX[k][x];
            int ya = sYA[k][y], yb = sYB[k][y], xa = sXA[k][x], xb = sXB[k][x];
            float v00 = img[ya * HMD + xa];
            float v01 = img[ya * HMD + xb];
            float v10 = img[yb * HMD + xa];
            float v11 = img[yb * HMD + xb];
            float top = (1.0f - wx) * v00 + wx * v01;
            float bot = (1.0f - wx) * v10 + wx * v11;
            float val = (1.0f - wy) * top + wy * bot;
            vals[k] = val * sc + tc;
        }
        float da = vals[0] - vals[1] + 1e-6f; spd += da * da;
        float dn = vals[0] - vals[2] + 1e-6f; snd += dn * dn;
    }
    block_reduce2(spd, snd);
    if (tid == 0) {
        atomicAdd(&ws_out[WS_PD2 + pair], spd);
        atomicAdd(&ws_out[WS_ND2 + pair], snd);
    }
}

// grid = 128, block = 256: exactly 32768 threads, one float4 each (131072 elems)
__global__ void focal(const float* __restrict__ hm, const float* __restrict__ gt,
                      float* __restrict__ ws) {
    int i = blockIdx.x * 256 + threadIdx.x;
    float4 hv = ((const float4*)hm)[i];
    float4 gv = ((const float4*)gt)[i];
    float lsum = 0.f, npos = 0.f;
    #pragma unroll
    for (int j = 0; j < 4; ++j) {
        float x = (&hv.x)[j], g = (&gv.x)[j];
        float pred = 1.0f / (1.0f + expf(-x));
        pred = fminf(fmaxf(pred, 1e-4f), 1.0f - 1e-4f);
        if (g == 1.0f) {
            float om = 1.0f - pred;
            lsum += logf(pred) * om * om;
            npos += 1.0f;
        } else {
            float gg = 1.0f - g;
            float g2 = gg * gg;
            lsum += logf(1.0f - pred) * pred * pred * (g2 * g2);
        }
    }
    block_reduce2(lsum, npos);
    if (threadIdx.x == 0) {
        atomicAdd(&ws[WS_LOSS], lsum);
        atomicAdd(&ws[WS_NPOS], npos);
    }
}

// 1 block, 64 threads (one wave)
__global__ void finalize(const float* __restrict__ ws, float* __restrict__ out) {
    int lane = threadIdx.x;
    float term = 0.f;
    if (lane < NPAIR) {
        float pd = sqrtf(ws[WS_PD2 + lane]);
        float nd = sqrtf(ws[WS_ND2 + lane]);
        term = fmaxf(0.1f + pd - nd, 0.0f);
    }
    #pragma unroll
    for (int off = 8; off > 0; off >>= 1) term += __shfl_down(term, off, 64);
    if (lane == 0) {
        float trip = term * (1.0f / (float)NPAIR);
        float hm_loss = -ws[WS_LOSS] / fmaxf(ws[WS_NPOS], 1.0f);
        out[0] = hm_loss + trip;
    }
}

extern "C" void kernel_launch(void* const* d_in, const int* in_sizes, int n_in,
                              void* d_out, int out_size, void* d_ws, size_t ws_size,
                              hipStream_t stream) {
    const float* simi  = (const float*)d_in[0];
    const float* hm    = (const float*)d_in[1];
    const float* hm_gt = (const float*)d_in[2];
    const int*   bboxf = (const int*)d_in[3];
    const int*   bboxm = (const int*)d_in[4];
    const float* gamma = (const float*)d_in[5];
    const float* beta  = (const float*)d_in[6];
    float* out = (float*)d_out;
    float* ws  = (float*)d_ws;

    hipMemsetAsync(ws, 0, WS_NZERO * sizeof(float), stream);
    chan_sums<<<2048, 256, 0, stream>>>(simi, ws);
    scales<<<1, 256, 0, stream>>>(gamma, beta, ws);
    triplet_partial<<<NPAIR * 8, 256, 0, stream>>>(simi, bboxf, bboxm, ws, ws);
    focal<<<128, 256, 0, stream>>>(hm, hm_gt, ws);
    finalize<<<1, 64, 0, stream>>>(ws, out);
}

// Round 2
// 34.828 us; speedup vs baseline: 1.6006x; 1.6006x over previous
//
#include <hip/hip_runtime.h>
#include <math.h>

#define CCH 256
#define HMD 128
#define HW (HMD*HMD)          // 16384
#define NTOT (8*HW)           // 131072 per channel
#define OH 11
#define OW 8
#define NPIX (OH*OW)          // 88
#define NPAIR 16

// ws float layout (all slots written unconditionally each call -> no memset):
// [0..2047]       chan sum partial, one per (b*256+c) plane block
// [2048..4095]    chan sumsq partial
// [4096..20479]   triplet partials: ((pair*256+c)*4) + {A1pd, A2pd, A1nd, A2nd}
// [20480..20735]  focal partials: 128 x {lsum, npos}
#define CH_SUM 0
#define CH_SQ  2048
#define TRI    4096
#define FOC    20480

__device__ __forceinline__ void block_reduce2(float& a, float& b) {
    // assumes blockDim.x == 256
    #pragma unroll
    for (int off = 32; off > 0; off >>= 1) {
        a += __shfl_down(a, off, 64);
        b += __shfl_down(b, off, 64);
    }
    __shared__ float sa[4], sb[4];
    int wid  = threadIdx.x >> 6;
    int lane = threadIdx.x & 63;
    if (lane == 0) { sa[wid] = a; sb[wid] = b; }
    __syncthreads();
    if (threadIdx.x == 0) {
        a = sa[0] + sa[1] + sa[2] + sa[3];
        b = sb[0] + sb[1] + sb[2] + sb[3];
    }
}

// grid = 128 (triplet) + 128 (focal) + 2048 (chan) = 2304 blocks, 256 threads.
// Triplet/focal first so their latency-bound work overlaps the streaming read.
__global__ void mega(const float* __restrict__ simi,
                     const float* __restrict__ hm,
                     const float* __restrict__ gt,
                     const int* __restrict__ bboxf,
                     const int* __restrict__ bboxm,
                     float* __restrict__ ws) {
    const int bid = blockIdx.x;
    const int tid = threadIdx.x;

    if (bid < 128) {
        // ---- triplet partial: pair = bid>>3, channels slice*32..slice*32+31 ----
        int pair  = bid >> 3;
        int slice = bid & 7;

        __shared__ int   sYA[3][OH], sYB[3][OH], sXA[3][OW], sXB[3][OW];
        __shared__ float sWY[3][OH], sWX[3][OW];
        __shared__ int   sBase[3];

        if (tid < 3) {
            const int* bx;
            int bidx;
            if (tid == 0)      { bx = bboxf + pair * 4;        bidx = pair >> 2; }       // anchor
            else if (tid == 1) { bx = bboxf + (16 + pair) * 4; bidx = 4 + (pair >> 2); } // positive
            else               { bx = bboxm + pair * 4;        bidx = pair >> 1; }       // negative
            int x0 = bx[0], y0 = bx[1], x1 = bx[2], y1 = bx[3];
            float h = (float)(y1 - y0), w = (float)(x1 - x0);
            for (int j = 0; j < OH; ++j) {
                float sy = fminf(fmaxf((j + 0.5f) * h / (float)OH - 0.5f, 0.0f), h - 1.0f);
                int ylo = (int)floorf(sy);
                sYA[tid][j] = y0 + ylo;
                sYB[tid][j] = y0 + min(ylo + 1, y1 - y0 - 1);
                sWY[tid][j] = sy - (float)ylo;
            }
            for (int j = 0; j < OW; ++j) {
                float sx = fminf(fmaxf((j + 0.5f) * w / (float)OW - 0.5f, 0.0f), w - 1.0f);
                int xlo = (int)floorf(sx);
                sXA[tid][j] = x0 + xlo;
                sXB[tid][j] = x0 + min(xlo + 1, x1 - x0 - 1);
                sWX[tid][j] = sx - (float)xlo;
            }
            sBase[tid] = bidx * CCH * HW;
        }
        __syncthreads();

        int cl = tid >> 3;          // 0..31: channel within slice
        int lx = tid & 7;           // output column
        int c  = slice * 32 + cl;

        const float* imgA = simi + sBase[0] + c * HW;
        const float* imgP = simi + sBase[1] + c * HW;
        const float* imgN = simi + sBase[2] + c * HW;

        float a1p = 0.f, a2p = 0.f, a1n = 0.f, a2n = 0.f;
        float wxA = sWX[0][lx], wxP = sWX[1][lx], wxN = sWX[2][lx];
        int xaA = sXA[0][lx], xbA = sXB[0][lx];
        int xaP = sXA[1][lx], xbP = sXB[1][lx];
        int xaN = sXA[2][lx], xbN = sXB[2][lx];

        #pragma unroll
        for (int y = 0; y < OH; ++y) {
            float wyA = sWY[0][y], wyP = sWY[1][y], wyN = sWY[2][y];
            int yaA = sYA[0][y] * HMD, ybA = sYB[0][y] * HMD;
            int yaP = sYA[1][y] * HMD, ybP = sYB[1][y] * HMD;
            int yaN = sYA[2][y] * HMD, ybN = sYB[2][y] * HMD;

            float vA, vP, vN;
            {
                float v00 = imgA[yaA + xaA], v01 = imgA[yaA + xbA];
                float v10 = imgA[ybA + xaA], v11 = imgA[ybA + xbA];
                float top = (1.0f - wxA) * v00 + wxA * v01;
                float bot = (1.0f - wxA) * v10 + wxA * v11;
                vA = (1.0f - wyA) * top + wyA * bot;
            }
            {
                float v00 = imgP[yaP + xaP], v01 = imgP[yaP + xbP];
                float v10 = imgP[ybP + xaP], v11 = imgP[ybP + xbP];
                float top = (1.0f - wxP) * v00 + wxP * v01;
                float bot = (1.0f - wxP) * v10 + wxP * v11;
                vP = (1.0f - wyP) * top + wyP * bot;
            }
            {
                float v00 = imgN[yaN + xaN], v01 = imgN[yaN + xbN];
                float v10 = imgN[ybN + xaN], v11 = imgN[ybN + xbN];
                float top = (1.0f - wxN) * v00 + wxN * v01;
                float bot = (1.0f - wxN) * v10 + wxN * v11;
                vN = (1.0f - wyN) * top + wyN * bot;
            }
            float dp = vA - vP; a1p += dp; a2p += dp * dp;
            float dn = vA - vN; a1n += dn; a2n += dn * dn;
        }
        // reduce across the 8 lanes sharing a channel (consecutive lanes)
        #pragma unroll
        for (int off = 4; off > 0; off >>= 1) {
            a1p += __shfl_down(a1p, off, 8);
            a2p += __shfl_down(a2p, off, 8);
            a1n += __shfl_down(a1n, off, 8);
            a2n += __shfl_down(a2n, off, 8);
        }
        if (lx == 0) {
            float* q = ws + TRI + (pair * 256 + c) * 4;
            q[0] = a1p; q[1] = a2p; q[2] = a1n; q[3] = a2n;
        }
    } else if (bid < 256) {
        // ---- focal partial ----
        int f = bid - 128;
        int i = f * 256 + tid;
        float4 hv = ((const float4*)hm)[i];
        float4 gv = ((const float4*)gt)[i];
        float lsum = 0.f, npos = 0.f;
        #pragma unroll
        for (int j = 0; j < 4; ++j) {
            float x = (&hv.x)[j], g = (&gv.x)[j];
            float pred = 1.0f / (1.0f + expf(-x));
            pred = fminf(fmaxf(pred, 1e-4f), 1.0f - 1e-4f);
            if (g == 1.0f) {
                float om = 1.0f - pred;
                lsum += logf(pred) * om * om;
                npos += 1.0f;
            } else {
                float gg = 1.0f - g;
                float g2 = gg * gg;
                lsum += logf(1.0f - pred) * pred * pred * (g2 * g2);
            }
        }
        block_reduce2(lsum, npos);
        if (tid == 0) { ws[FOC + 2 * f] = lsum; ws[FOC + 2 * f + 1] = npos; }
    } else {
        // ---- channel-plane sums: plane p = bid-256 = b*256 + c ----
        int p = bid - 256;
        const float4* p4 = (const float4*)(simi + (size_t)p * HW);
        float s = 0.f, s2 = 0.f;
        #pragma unroll
        for (int it = 0; it < 16; ++it) {
            float4 v = p4[it * 256 + tid];
            s  += v.x + v.y + v.z + v.w;
            s2 += v.x*v.x + v.y*v.y + v.z*v.z + v.w*v.w;
        }
        block_reduce2(s, s2);
        if (tid == 0) { ws[CH_SUM + p] = s; ws[CH_SQ + p] = s2; }
    }
}

// 1 block, 256 threads
__global__ void finalize(const float* __restrict__ ws,
                         const float* __restrict__ gamma,
                         float* __restrict__ out) {
    __shared__ float s_sh[256], tr[NPAIR];
    int t = threadIdx.x;

    // per-channel scale from the 8 plane partials (stride 256)
    float su = 0.f, sq = 0.f;
    #pragma unroll
    for (int b = 0; b < 8; ++b) {
        su += ws[CH_SUM + b * 256 + t];
        sq += ws[CH_SQ  + b * 256 + t];
    }
    const float invn = 1.0f / (float)NTOT;
    float mean = su * invn;
    float var  = sq * invn - mean * mean;
    s_sh[t] = gamma[t] / sqrtf(var + 1e-5f);
    __syncthreads();

    // pair distances: pair = t>>4, each of 16 lanes handles 16 channels
    int pair = t >> 4, cl = t & 15;
    float pdl = 0.f, ndl = 0.f;
    #pragma unroll
    for (int k = 0; k < 16; ++k) {
        int c = cl + 16 * k;
        float s = s_sh[c];
        const float* q = ws + TRI + (pair * 256 + c) * 4;
        pdl += s * s * q[1] + 2e-6f * s * q[0];
        ndl += s * s * q[3] + 2e-6f * s * q[2];
    }
    #pragma unroll
    for (int off = 8; off > 0; off >>= 1) {
        pdl += __shfl_down(pdl, off, 16);
        ndl += __shfl_down(ndl, off, 16);
    }
    if (cl == 0) {
        const float e2 = 1e-12f * (float)(CCH * NPIX);   // Σ eps^2 term
        tr[pair] = fmaxf(0.1f + sqrtf(pdl + e2) - sqrtf(ndl + e2), 0.0f);
    }

    // focal totals
    float l = 0.f, np = 0.f;
    if (t < 128) { l = ws[FOC + 2 * t]; np = ws[FOC + 2 * t + 1]; }
    block_reduce2(l, np);   // contains the __syncthreads covering tr[] writes

    if (t == 0) {
        float trip = 0.f;
        #pragma unroll
        for (int p = 0; p < NPAIR; ++p) trip += tr[p];
        trip *= (1.0f / (float)NPAIR);
        out[0] = -l / fmaxf(np, 1.0f) + trip;
    }
}

extern "C" void kernel_launch(void* const* d_in, const int* in_sizes, int n_in,
                              void* d_out, int out_size, void* d_ws, size_t ws_size,
                              hipStream_t stream) {
    const float* simi  = (const float*)d_in[0];
    const float* hm    = (const float*)d_in[1];
    const float* hm_gt = (const float*)d_in[2];
    const int*   bboxf = (const int*)d_in[3];
    const int*   bboxm = (const int*)d_in[4];
    const float* gamma = (const float*)d_in[5];
    float* out = (float*)d_out;
    float* ws  = (float*)d_ws;

    mega<<<2304, 256, 0, stream>>>(simi, hm, hm_gt, bboxf, bboxm, ws);
    finalize<<<1, 256, 0, stream>>>(ws, gamma, out);
}